// Round 17
// baseline (189.856 us; speedup 1.0000x reference)
//
#include <hip/hip_runtime.h>
#include <hip/hip_bf16.h>
#include <cstdint>
#include <cstddef>

#define SCALE1 0.17677669529663687f   // 1/sqrt(32)
#define POSE_ELEMS 50331648ll

typedef __attribute__((ext_vector_type(8))) short bf16x8;
typedef __attribute__((ext_vector_type(4))) float f32x4;

__device__ __forceinline__ unsigned short f2b(float f){
    unsigned int u = __float_as_uint(f);
    u = (u + 0x7FFFu + ((u >> 16) & 1u)) >> 16;   // RNE
    return (unsigned short)u;
}
__device__ __forceinline__ float b2f(unsigned short s){
    return __uint_as_float(((unsigned int)s) << 16);
}
__device__ __forceinline__ float wredsum(float v){
    #pragma unroll
    for (int m = 1; m < 64; m <<= 1) v += __shfl_xor(v, m);
    return v;
}

// ---------- K0: all weights -> bf16 in GEMM-ready layouts ----------
__global__ __launch_bounds__(256) void k_conv2(
    const float* __restrict__ wqkv1, const float* __restrict__ wo1,
    const float* __restrict__ wqkv2, const float* __restrict__ wo2,
    unsigned short* __restrict__ wk1b,  unsigned short* __restrict__ wv1b,
    unsigned short* __restrict__ wq2b,  unsigned short* __restrict__ wq1Tb,
    unsigned short* __restrict__ wk2Tb, unsigned short* __restrict__ wo1b,
    unsigned short* __restrict__ wv2b,  unsigned short* __restrict__ wo2b)
{
    int t = blockIdx.x * 256 + threadIdx.x;     // 65536
    int r = t >> 8, c = t & 255;
    wk1b[t] = f2b(wqkv1[(size_t)(256+r)*256 + c]);
    wv1b[t] = f2b(wqkv1[(size_t)(512+r)*256 + c]);
    wq2b[t] = f2b(wqkv2[t]);
    wo1b[t] = f2b(wo1[t]);
    wv2b[t] = f2b(wqkv2[(size_t)(512+r)*256 + c]);
    wo2b[t] = f2b(wo2[t]);
    wq1Tb[(size_t)c*256 + r] = f2b(wqkv1[t]);                       // wq1T[c][j]
    wk2Tb[(size_t)c*256 + r] = f2b(wqkv2[(size_t)(256+r)*256 + c]); // wk2T[i][d]
}

// ---------- K1: MFMA prep. Block = (bt, head-half), 512 blocks. ----------
__global__ __launch_bounds__(512) void k_prep2(
    const float* __restrict__ cam, const float* __restrict__ ln2g, const float* __restrict__ ln2b,
    const float* __restrict__ bqkv1, const float* __restrict__ bqkv2,
    const unsigned short* __restrict__ wk1b,  const unsigned short* __restrict__ wv1b,
    const unsigned short* __restrict__ wq2b,  const unsigned short* __restrict__ wq1Tb,
    const unsigned short* __restrict__ wk2Tb, const unsigned short* __restrict__ wo1b,
    unsigned short* __restrict__ ckb, unsigned short* __restrict__ wv_oTb,
    unsigned short* __restrict__ uwb, float* __restrict__ cb1w)
{
    __shared__ __align__(16) unsigned short cln[2*4224];   // camb | cnb; Phase C: stg overlay (16 KB)
    __shared__ __align__(16) unsigned short kcs [16*264];
    __shared__ __align__(16) unsigned short vcs [16*264];
    __shared__ __align__(16) unsigned short q2s [16*264];
    unsigned short* camb = cln;
    unsigned short* cnb  = cln + 4224;

    int tid = threadIdx.x;
    int wid = tid >> 6, lane = tid & 63;
    int fr = lane & 15, hi4 = lane >> 4, fk = hi4 * 8;
    int bt = blockIdx.x >> 1;
    int hf = blockIdx.x & 1;            // this block handles heads hf*4..hf*4+3
    int r0 = bt * 8;

    // Phase A: 8 cam rows, LN, raw+ln bf16; zero rows 8-15
    {
        float4 g2v = ((const float4*)ln2g)[lane];
        float4 b2v = ((const float4*)ln2b)[lane];
        int row = wid;
        float4 f = ((const float4*)(cam + (size_t)(r0+row)*256))[lane];
        float s  = wredsum(f.x+f.y+f.z+f.w);
        float s2 = wredsum(f.x*f.x+f.y*f.y+f.z*f.z+f.w*f.w);
        float mu = s * (1.f/256.f);
        float rs = rsqrtf(s2*(1.f/256.f) - mu*mu + 1e-5f);
        ushort4 rawv, lnv;
        rawv.x = f2b(f.x); rawv.y = f2b(f.y); rawv.z = f2b(f.z); rawv.w = f2b(f.w);
        lnv.x = f2b((f.x-mu)*rs*g2v.x + b2v.x);
        lnv.y = f2b((f.y-mu)*rs*g2v.y + b2v.y);
        lnv.z = f2b((f.z-mu)*rs*g2v.z + b2v.z);
        lnv.w = f2b((f.w-mu)*rs*g2v.w + b2v.w);
        *(ushort4*)&camb[row*264 + lane*4] = rawv;
        *(ushort4*)&cnb [row*264 + lane*4] = lnv;
        for (int e = tid; e < 2112; e += 512){      // rows 8..15 zeroed
            int off = 8*264 + e;
            camb[off] = 0; cnb[off] = 0; kcs[off] = 0; vcs[off] = 0; q2s[off] = 0;
        }
    }
    __syncthreads();

    // Phase B: 3 GEMMs (kc, vc, q2) restricted to this hf's 128 cols
    for (int u = wid; u < 24; u += 8){
        int gm = u >> 3, nt = u & 7;
        const unsigned short* As = (gm == 2) ? cnb : camb;
        const unsigned short* Bw = (gm == 0) ? wk1b : (gm == 1) ? wv1b : wq2b;
        const float* bias = (gm == 0) ? (bqkv1 + 256) : (gm == 1) ? (bqkv1 + 512) : bqkv2;
        unsigned short* Dst = (gm == 0) ? kcs : (gm == 1) ? vcs : q2s;
        int col = hf*128 + nt*16 + fr;
        float bc = bias[col];
        f32x4 acc = (f32x4){0.f,0.f,0.f,0.f};
        for (int k0 = 0; k0 < 256; k0 += 32){
            bf16x8 a = *(const bf16x8*)&As[fr*264 + k0 + fk];
            bf16x8 b = *(const bf16x8*)&Bw[(size_t)col*256 + k0 + fk];
            acc = __builtin_amdgcn_mfma_f32_16x16x32_bf16(a, b, acc, 0, 0, 0);
        }
        if (hi4 < 2){
            #pragma unroll
            for (int i = 0; i < 4; i++)
                Dst[(hi4*4 + i)*264 + col] = f2b(acc[i] + bc);
        }
    }
    __syncthreads();

    // cb1 for this hf's 4 heads
    if (tid < 32){
        int th = tid >> 3, kk = tid & 7;
        int h = hf*4 + th;
        float a = 0.f;
        for (int j = 0; j < 32; j++)
            a += bqkv1[h*32 + j] * b2f(kcs[kk*264 + h*32 + j]);
        cb1w[(size_t)bt*64 + h*8 + kk] = a;
    }

    // Phase C: 3 rounds (ot); frags -> stg overlay (16 KB), coop 16B stores
    unsigned short* stg = cln;
    for (int ot = 0; ot < 3; ot++){
        const unsigned short* As = (ot == 0) ? kcs : (ot == 1) ? q2s : vcs;
        const unsigned short* Bw = (ot == 0) ? wq1Tb : (ot == 1) ? wk2Tb : wo1b;
        __syncthreads();          // previous round's stg readers (or Phase A/B cln readers) done
        int hp = wid & 3;
        int h  = hf*4 + hp;
        int ntb = (wid >> 2) * 8;
        bf16x8 a = *(const bf16x8*)&As[fr*264 + h*32 + fk];
        for (int nt = ntb; nt < ntb + 8; nt++){
            int col = nt*16 + fr;
            bf16x8 b = *(const bf16x8*)&Bw[(size_t)col*256 + h*32 + fk];
            f32x4 acc = __builtin_amdgcn_mfma_f32_16x16x32_bf16(a, b, (f32x4){0.f,0.f,0.f,0.f}, 0, 0, 0);
            if (hi4 < 2){
                int kk0 = hi4*4;
                if (ot == 0){
                    #pragma unroll
                    for (int i = 0; i < 4; i++) stg[(hp*8 + kk0 + i)*256 + col] = f2b(acc[i]);
                } else if (ot == 1){
                    #pragma unroll
                    for (int i = 0; i < 4; i++) stg[(kk0 + i)*1024 + hp*256 + col] = f2b(acc[i]);
                } else {
                    ushort4 wv;
                    wv.x = f2b(acc[0]); wv.y = f2b(acc[1]); wv.z = f2b(acc[2]); wv.w = f2b(acc[3]);
                    *(ushort4*)&stg[col*32 + hp*8 + kk0] = wv;
                }
            }
        }
        __syncthreads();
        unsigned short* dst = (ot == 0) ? ckb : (ot == 1) ? uwb : wv_oTb;
        for (int cj = tid; cj < 1024; cj += 512){
            bf16x8 v = ((const bf16x8*)stg)[cj];
            size_t go;
            if (ot == 0){
                go = (size_t)bt*16384 + (size_t)hf*8192 + (size_t)cj*8;
            } else if (ot == 1){
                int r = cj >> 7, w = (cj*8) & 1023;
                go = (size_t)bt*16384 + (size_t)r*2048 + (size_t)hf*1024 + w;
            } else {
                int c = cj >> 2, v2 = (cj & 3)*8;
                go = (size_t)bt*16384 + (size_t)c*64 + (size_t)hf*32 + v2;
            }
            *(bf16x8*)(dst + go) = v;
        }
    }
}

// ---------- K2: 32-row third-group block, stage1 + stage2 partials ----------
// Round-17: block = 32 rows (96 = 3x32, 6144 blocks). LDS 21.25 KB -> 7
// blocks/CU = 28-wave residency cap (was 5 blocks/20 waves at 48 rows).
// Stage-2 partial PV is K=32 exactly: single MFMA step, no row clamp.
// VGPR <= 64 held (r16); P5 re-reads pose (cache-absorbed); k_cam2 combines
// 3 partials per g (3-way flash softmax merge).
__global__ __launch_bounds__(256) void k_pose(
    const float* __restrict__ pose,
    const float* __restrict__ ln1g, const float* __restrict__ ln1b,
    const float* __restrict__ bo1,
    const unsigned short* __restrict__ ckb, const unsigned short* __restrict__ wv_oTb,
    const float* __restrict__ cb1w, const unsigned short* __restrict__ uwb,
    float* __restrict__ out, unsigned short* __restrict__ ypw, float* __restrict__ yms)
{
    __shared__ __align__(16) unsigned short Xs[32*256];   // swizzled: byte^=((row&7)<<4)
    __shared__ __align__(16) unsigned short A1u[2688];    // A1[32][72] | {pb[16][40]@0, sc[8][32]f32 @1280B, ystg @1280B+1024}

    int tid = threadIdx.x;
    int bid = blockIdx.x;
    int g3 = (bid & 7) * 768 + (bid >> 3);     // bijective XCD swizzle (6144 = 8*768)
    int g = g3 / 3, part = g3 - g*3;
    int bt = g >> 3;
    int wid = tid >> 6, lane = tid & 63;
    int fr = lane & 15, hi4 = lane >> 4, fk = hi4 * 8;

    unsigned short (*A1)[72] = (unsigned short(*)[72])A1u;
    unsigned short (*pb)[40] = (unsigned short(*)[40])A1u;           // P7/P8
    float (*sc)[32] = (float(*)[32])((char*)A1u + 1280);             // P6/P7
    unsigned short* ystg = (unsigned short*)((char*)A1u + 2304);     // P8 [8][256] -> wait: need 4096B

    const float* pbase = pose + (size_t)g*96*256 + (size_t)part*32*256;
    float* obase = out + (size_t)g*96*256 + (size_t)part*32*256;

    int n1 = wid*16 + fr;                       // score col 0..63 (h = n1>>3, kk = n1&7)
    const unsigned short* ckg = ckb + ((size_t)bt*64 + n1) * 256;
    float cb = cb1w[(size_t)bt*64 + n1];

    // P1: LN(pose) -> Xs (rows 0..31; wave w owns rows w, w+4, ...)
    {
        float4 g1 = ((const float4*)ln1g)[lane];
        float4 b1 = ((const float4*)ln1b)[lane];
        #pragma unroll
        for (int rr = 0; rr < 8; rr++){
            int r = wid + rr*4;
            float4 f = ((const float4*)pbase)[(size_t)r * 64 + lane];
            float s  = wredsum(f.x+f.y+f.z+f.w);
            float s2 = wredsum(f.x*f.x+f.y*f.y+f.z*f.z+f.w*f.w);
            float mu = s * (1.f/256.f);
            float rs = rsqrtf(s2*(1.f/256.f) - mu*mu + 1e-5f);
            ushort4 qv;
            qv.x = f2b((f.x-mu)*rs*g1.x + b1.x);
            qv.y = f2b((f.y-mu)*rs*g1.y + b1.y);
            qv.z = f2b((f.z-mu)*rs*g1.z + b1.z);
            qv.w = f2b((f.w-mu)*rs*g1.w + b1.w);
            *(ushort4*)((char*)Xs + r*512 + ((lane*8) ^ ((r&7)<<4))) = qv;
        }
    }
    __syncthreads();   // b1

    // P2: score GEMM (32x64, K=256) + softmax over kk -> A1
    {
        f32x4 acc[2];
        acc[0] = (f32x4){0.f,0.f,0.f,0.f};
        acc[1] = (f32x4){0.f,0.f,0.f,0.f};
        #pragma unroll
        for (int kt = 0; kt < 8; kt++){
            int k0 = kt * 32;
            bf16x8 b = *(const bf16x8*)(ckg + k0 + fk);
            #pragma unroll
            for (int mt = 0; mt < 2; mt++){
                int r = mt*16 + fr;
                bf16x8 a = *(const bf16x8*)((char*)Xs + r*512 + (((k0+fk)*2) ^ ((r&7)<<4)));
                acc[mt] = __builtin_amdgcn_mfma_f32_16x16x32_bf16(a, b, acc[mt], 0, 0, 0);
            }
        }
        #pragma unroll
        for (int mt = 0; mt < 2; mt++){
            #pragma unroll
            for (int i = 0; i < 4; i++){
                float s = (acc[mt][i] + cb) * SCALE1;
                float mx = s;
                mx = fmaxf(mx, __shfl_xor(mx, 1));
                mx = fmaxf(mx, __shfl_xor(mx, 2));
                mx = fmaxf(mx, __shfl_xor(mx, 4));
                float e = __expf(s - mx);
                float sm = e;
                sm += __shfl_xor(sm, 1);
                sm += __shfl_xor(sm, 2);
                sm += __shfl_xor(sm, 4);
                A1[mt*16 + hi4*4 + i][n1] = f2b(e / sm);
            }
        }
    }
    __syncthreads();   // b2

    // P4: PV GEMM (32x256, K=64): one 16-col tile per jt iteration (low reg)
    {
        const unsigned short* wvg = wv_oTb + (size_t)bt * 256 * 64;
        #pragma unroll
        for (int jt = 0; jt < 4; jt++){
            int col = wid*64 + jt*16 + fr;
            f32x4 acc2[2];
            acc2[0] = (f32x4){0.f,0.f,0.f,0.f};
            acc2[1] = (f32x4){0.f,0.f,0.f,0.f};
            #pragma unroll
            for (int k0 = 0; k0 < 64; k0 += 32){
                bf16x8 b = *(const bf16x8*)(wvg + (size_t)col*64 + k0 + fk);
                #pragma unroll
                for (int mt = 0; mt < 2; mt++){
                    bf16x8 a = *(const bf16x8*)&A1[mt*16 + fr][k0 + fk];
                    acc2[mt] = __builtin_amdgcn_mfma_f32_16x16x32_bf16(a, b, acc2[mt], 0, 0, 0);
                }
            }
            float bias = bo1[col];
            #pragma unroll
            for (int mt = 0; mt < 2; mt++)
                #pragma unroll
                for (int i = 0; i < 4; i++){
                    int row = mt*16 + hi4*4 + i;
                    *(unsigned short*)((char*)Xs + row*512 + ((col*2) ^ ((row&7)<<4))) = f2b(acc2[mt][i] + bias);
                }
        }
    }
    __syncthreads();   // b3

    // P5: residual: re-read pose (cache-absorbed), out = pose + o1(Xs); Xs <- pose_out bf16
    {
        #pragma unroll
        for (int rr = 0; rr < 8; rr++){
            int r = wid + rr*4;
            float4 f = ((const float4*)pbase)[(size_t)r * 64 + lane];
            char* px = (char*)Xs + r*512 + ((lane*8) ^ ((r&7)<<4));
            ushort4 ov = *(ushort4*)px;
            float4 val;
            val.x = f.x + b2f(ov.x);
            val.y = f.y + b2f(ov.y);
            val.z = f.z + b2f(ov.z);
            val.w = f.w + b2f(ov.w);
            *(float4*)(obase + (size_t)r*256 + lane*4) = val;
            ushort4 nv;
            nv.x = f2b(val.x); nv.y = f2b(val.y); nv.z = f2b(val.z); nv.w = f2b(val.w);
            *(ushort4*)px = nv;
        }
    }
    __syncthreads();   // b4

    // P6: stage-2 scores sc[h][n] = SCALE * u_h . x_n  (waves 0-1, 32 rows)
    if (wid < 2){
        const unsigned short* ug = uwb + (size_t)g*2048;
        f32x4 a6 = (f32x4){0.f,0.f,0.f,0.f};
        for (int k0 = 0; k0 < 256; k0 += 32){
            bf16x8 u = *(const bf16x8*)(ug + (size_t)(fr & 7)*256 + k0 + fk); // head fr&7
            int r = wid*16 + fr;
            bf16x8 x = *(const bf16x8*)((char*)Xs + r*512 + (((k0+fk)*2) ^ ((r&7)<<4)));
            a6 = __builtin_amdgcn_mfma_f32_16x16x32_bf16(u, x, a6, 0, 0, 0);
        }
        if (hi4 < 2){
            #pragma unroll
            for (int i = 0; i < 4; i++)
                sc[hi4*4 + i][wid*16 + fr] = a6[i] * SCALE1;
        }
    }
    __syncthreads();   // b5

    // P7: partial softmax (wave 0): 4 values/lane over local 32 -> pb, (m,s) -> yms
    if (wid == 0){
        int h = lane >> 3, j = lane & 7;
        float v[4];
        #pragma unroll
        for (int q = 0; q < 4; q++) v[q] = sc[h][j*4 + q];
        float mx = fmaxf(fmaxf(v[0], v[1]), fmaxf(v[2], v[3]));
        mx = fmaxf(mx, __shfl_xor(mx, 1));
        mx = fmaxf(mx, __shfl_xor(mx, 2));
        mx = fmaxf(mx, __shfl_xor(mx, 4));
        float e[4], s = 0.f;
        #pragma unroll
        for (int q = 0; q < 4; q++){ e[q] = __expf(v[q] - mx); s += e[q]; }
        s += __shfl_xor(s, 1);
        s += __shfl_xor(s, 2);
        s += __shfl_xor(s, 4);
        #pragma unroll
        for (int q = 0; q < 4; q++) pb[h][j*4 + q] = f2b(e[q]);
        if (j == 0){
            yms[(size_t)g3*16 + h*2]     = mx;
            yms[(size_t)g3*16 + h*2 + 1] = s;
        }
    }
    __syncthreads();   // b6

    // P8: partial PV2 (K=32, single MFMA step) -> ystg, coalesced ypw store
    // NOTE: pb rows 8-15 hold stale-but-finite A1 bytes; their garbage only
    // pollutes output rows 8-15 which are discarded (hi4<2 keeps rows 0-7).
    {
        bf16x8 a8 = *(const bf16x8*)&pb[fr][fk];
        #pragma unroll
        for (int nth = 0; nth < 2; nth++){    // 2 col tiles at a time (reg diet)
            f32x4 ay[2];
            ay[0] = (f32x4){0.f,0.f,0.f,0.f};
            ay[1] = (f32x4){0.f,0.f,0.f,0.f};
            #pragma unroll
            for (int nt = 0; nt < 2; nt++){
                int col = wid*64 + (nth*2+nt)*16 + fr;
                union { bf16x8 v; unsigned short u[8]; } bx;
                #pragma unroll
                for (int jj = 0; jj < 8; jj++){
                    int rr = fk + jj;          // 0..31, all valid rows
                    bx.u[jj] = *(const unsigned short*)((char*)Xs + rr*512 + ((col*2) ^ ((rr&7)<<4)));
                }
                ay[nt] = __builtin_amdgcn_mfma_f32_16x16x32_bf16(a8, bx.v, ay[nt], 0, 0, 0);
            }
            if (hi4 < 2){
                #pragma unroll
                for (int nt = 0; nt < 2; nt++)
                    #pragma unroll
                    for (int i = 0; i < 4; i++)
                        ystg[(hi4*4 + i)*256 + wid*64 + (nth*2+nt)*16 + fr] = f2b(ay[nt][i]);
            }
        }
    }
    __syncthreads();   // b7
    ((bf16x8*)(ypw + (size_t)g3*2048))[tid] = ((const bf16x8*)ystg)[tid];
}

// ---------- K3: per-bt combine (3 partials) + camera matvecs via MFMA ----------
__global__ __launch_bounds__(512) void k_cam2(
    const float* __restrict__ cam,
    const float* __restrict__ bqkv2, const float* __restrict__ bo2,
    const unsigned short* __restrict__ wv2b, const unsigned short* __restrict__ wo2b,
    const unsigned short* __restrict__ ypw, const float* __restrict__ yms,
    float* __restrict__ out)
{
    __shared__ __align__(16) unsigned short ycb[8][16][264];  // [h][g pad16][256 pad]
    __shared__ __align__(16) unsigned short o2s[16][264];     // o2 bf16, rows g pad16
    __shared__ __align__(16) float wf[8][8][3];               // [gl][h]{f0,f1,f2}

    int tid = threadIdx.x;
    int bt = blockIdx.x;
    int wid = tid >> 6, lane = tid & 63;
    int fr = lane & 15, hi4 = lane >> 4, fk = hi4 * 8;

    // zero pad rows (g=8..15): finite A-rows for MFMA
    for (int e = tid; e < 16896; e += 512)
        ((unsigned short*)ycb)[(e/2112)*16*264 + (8 + (e%2112)/264)*264 + (e%264)] = 0;
    for (int e = tid; e < 2112; e += 512) o2s[8 + e/264][e%264] = 0;

    // combine factors (3-way flash merge)
    if (tid < 64){
        int gl = tid >> 3, h = tid & 7;
        size_t g3b = ((size_t)(bt*8 + gl)) * 3;
        float m0 = yms[(g3b+0)*16 + h*2],     s0 = yms[(g3b+0)*16 + h*2 + 1];
        float m1 = yms[(g3b+1)*16 + h*2],     s1 = yms[(g3b+1)*16 + h*2 + 1];
        float m2 = yms[(g3b+2)*16 + h*2],     s2 = yms[(g3b+2)*16 + h*2 + 1];
        float m = fmaxf(fmaxf(m0, m1), m2);
        float w0 = __expf(m0 - m), w1 = __expf(m1 - m), w2 = __expf(m2 - m);
        float inv = 1.f / (s0*w0 + s1*w1 + s2*w2);
        wf[gl][h][0] = w0*inv; wf[gl][h][1] = w1*inv; wf[gl][h][2] = w2*inv;
    }
    __syncthreads();

    // combine partials -> ycb bf16
    for (int e = tid; e < 2048; e += 512){
        int gl = e >> 8, rest = e & 255, h = rest >> 5, i8 = rest & 31;
        const unsigned short* y0 = ypw + ((size_t)(bt*8 + gl)*3)*2048 + h*256 + i8*8;
        bf16x8 v0 = *(const bf16x8*)y0;
        bf16x8 v1 = *(const bf16x8*)(y0 + 2048);
        bf16x8 v2 = *(const bf16x8*)(y0 + 4096);
        float f0 = wf[gl][h][0], f1 = wf[gl][h][1], f2 = wf[gl][h][2];
        union { bf16x8 v; unsigned short u[8]; } rr;
        #pragma unroll
        for (int q = 0; q < 8; q++)
            rr.u[q] = f2b(b2f((unsigned short)v0[q])*f0 + b2f((unsigned short)v1[q])*f1
                        + b2f((unsigned short)v2[q])*f2);
        *(bf16x8*)&ycb[h][gl][i8*8] = rr.v;
    }
    __syncthreads();

    // GEMM o2: per head h, D[g][j] = ycb_h @ wv2_h^T + bv2 (M=16pad, N=32, K=256)
    for (int u = wid; u < 16; u += 8){
        int h = u >> 1, nt = u & 1;
        int m = h*32 + nt*16 + fr;
        f32x4 acc = (f32x4){0.f,0.f,0.f,0.f};
        for (int k0 = 0; k0 < 256; k0 += 32){
            bf16x8 a = *(const bf16x8*)&ycb[h][fr][k0 + fk];
            bf16x8 b = *(const bf16x8*)(wv2b + (size_t)m*256 + k0 + fk);
            acc = __builtin_amdgcn_mfma_f32_16x16x32_bf16(a, b, acc, 0, 0, 0);
        }
        if (hi4 < 2){
            float bv = bqkv2[512 + m];
            #pragma unroll
            for (int i = 0; i < 4; i++)
                o2s[hi4*4 + i][m] = f2b(acc[i] + bv);
        }
    }
    __syncthreads();

    // GEMM cam_out: D[g][c] = o2s @ wo2^T + bo2 + cam (M=16pad, N=256, K=256)
    const float* camg = cam + (size_t)bt*8*256;
    float* og = out + POSE_ELEMS + (size_t)bt*8*256;
    for (int u = wid; u < 16; u += 8){
        int col = u*16 + fr;
        f32x4 acc = (f32x4){0.f,0.f,0.f,0.f};
        for (int k0 = 0; k0 < 256; k0 += 32){
            bf16x8 a = *(const bf16x8*)&o2s[fr][k0 + fk];
            bf16x8 b = *(const bf16x8*)(wo2b + (size_t)col*256 + k0 + fk);
            acc = __builtin_amdgcn_mfma_f32_16x16x32_bf16(a, b, acc, 0, 0, 0);
        }
        if (hi4 < 2){
            float bc = bo2[col];
            #pragma unroll
            for (int i = 0; i < 4; i++){
                int gg = hi4*4 + i;
                og[(size_t)gg*256 + col] = acc[i] + bc + camg[(size_t)gg*256 + col];
            }
        }
    }
}

extern "C" void kernel_launch(void* const* d_in, const int* in_sizes, int n_in,
                              void* d_out, int out_size, void* d_ws, size_t ws_size,
                              hipStream_t stream)
{
    const float* pose  = (const float*)d_in[0];
    const float* camr  = (const float*)d_in[1];
    const float* ln1g  = (const float*)d_in[2];
    const float* ln1b  = (const float*)d_in[3];
    const float* wqkv1 = (const float*)d_in[4];
    const float* bqkv1 = (const float*)d_in[5];
    const float* wo1   = (const float*)d_in[6];
    const float* bo1   = (const float*)d_in[7];
    const float* ln2g  = (const float*)d_in[8];
    const float* ln2b  = (const float*)d_in[9];
    const float* wqkv2 = (const float*)d_in[10];
    const float* bqkv2 = (const float*)d_in[11];
    const float* wo2   = (const float*)d_in[12];
    const float* bo2   = (const float*)d_in[13];
    float* out = (float*)d_out;
    char* ws = (char*)d_ws;

    // ws layout (~52 MB)
    size_t off = 0;
    unsigned short* ckb    = (unsigned short*)(ws + off); off += 8388608;          // [256][64][256] bf16
    unsigned short* wv_oTb = (unsigned short*)(ws + off); off += 8388608;          // [256][256][64] bf16
    unsigned short* uwb    = (unsigned short*)(ws + off); off += 8388608 + 8192;   // [2048][2048] bf16 + pad
    unsigned short* ypw    = (unsigned short*)(ws + off); off += 25165824;         // [6144][8][256] bf16
    float*          yms    = (float*)(ws + off);          off += 393216;           // [6144][8][2] f32
    unsigned short* wts    = (unsigned short*)(ws + off); off += 8*131072;
    unsigned short* wk1b  = wts;
    unsigned short* wv1b  = wts + 1*65536;
    unsigned short* wq2b  = wts + 2*65536;
    unsigned short* wq1Tb = wts + 3*65536;
    unsigned short* wk2Tb = wts + 4*65536;
    unsigned short* wo1b  = wts + 5*65536;
    unsigned short* wv2b  = wts + 6*65536;
    unsigned short* wo2b  = wts + 7*65536;
    float* cb1w = (float*)(ws + off);                      off += 65536;

    k_conv2<<<dim3(256), dim3(256), 0, stream>>>(wqkv1, wo1, wqkv2, wo2,
                                                 wk1b, wv1b, wq2b, wq1Tb, wk2Tb, wo1b, wv2b, wo2b);
    k_prep2<<<dim3(512), dim3(512), 0, stream>>>(camr, ln2g, ln2b, bqkv1, bqkv2,
                                                 wk1b, wv1b, wq2b, wq1Tb, wk2Tb, wo1b,
                                                 ckb, wv_oTb, uwb, cb1w);
    k_pose<<<dim3(6144), dim3(256), 0, stream>>>(pose, ln1g, ln1b, bo1,
                                                 ckb, wv_oTb, cb1w, uwb, out, ypw, yms);
    k_cam2<<<dim3(256), dim3(512), 0, stream>>>(camr, bqkv2, bo2, wv2b, wo2b, ypw, yms, out);
}

// Round 18
// 181.040 us; speedup vs baseline: 1.0487x; 1.0487x over previous
//
#include <hip/hip_runtime.h>
#include <hip/hip_bf16.h>
#include <cstdint>
#include <cstddef>

#define SCALE1 0.17677669529663687f   // 1/sqrt(32)
#define POSE_ELEMS 50331648ll

typedef __attribute__((ext_vector_type(8))) short bf16x8;
typedef __attribute__((ext_vector_type(4))) float f32x4;

__device__ __forceinline__ unsigned short f2b(float f){
    unsigned int u = __float_as_uint(f);
    u = (u + 0x7FFFu + ((u >> 16) & 1u)) >> 16;   // RNE
    return (unsigned short)u;
}
__device__ __forceinline__ float b2f(unsigned short s){
    return __uint_as_float(((unsigned int)s) << 16);
}
__device__ __forceinline__ float wredsum(float v){
    #pragma unroll
    for (int m = 1; m < 64; m <<= 1) v += __shfl_xor(v, m);
    return v;
}

// ---------- K0: all weights -> bf16 in GEMM-ready layouts ----------
__global__ __launch_bounds__(256) void k_conv2(
    const float* __restrict__ wqkv1, const float* __restrict__ wo1,
    const float* __restrict__ wqkv2, const float* __restrict__ wo2,
    unsigned short* __restrict__ wk1b,  unsigned short* __restrict__ wv1b,
    unsigned short* __restrict__ wq2b,  unsigned short* __restrict__ wq1Tb,
    unsigned short* __restrict__ wk2Tb, unsigned short* __restrict__ wo1b,
    unsigned short* __restrict__ wv2b,  unsigned short* __restrict__ wo2b)
{
    int t = blockIdx.x * 256 + threadIdx.x;     // 65536
    int r = t >> 8, c = t & 255;
    wk1b[t] = f2b(wqkv1[(size_t)(256+r)*256 + c]);
    wv1b[t] = f2b(wqkv1[(size_t)(512+r)*256 + c]);
    wq2b[t] = f2b(wqkv2[t]);
    wo1b[t] = f2b(wo1[t]);
    wv2b[t] = f2b(wqkv2[(size_t)(512+r)*256 + c]);
    wo2b[t] = f2b(wo2[t]);
    wq1Tb[(size_t)c*256 + r] = f2b(wqkv1[t]);                       // wq1T[c][j]
    wk2Tb[(size_t)c*256 + r] = f2b(wqkv2[(size_t)(256+r)*256 + c]); // wk2T[i][d]
}

// ---------- K1: MFMA prep. Block = (bt, head-half), 512 blocks. ----------
__global__ __launch_bounds__(512) void k_prep2(
    const float* __restrict__ cam, const float* __restrict__ ln2g, const float* __restrict__ ln2b,
    const float* __restrict__ bqkv1, const float* __restrict__ bqkv2,
    const unsigned short* __restrict__ wk1b,  const unsigned short* __restrict__ wv1b,
    const unsigned short* __restrict__ wq2b,  const unsigned short* __restrict__ wq1Tb,
    const unsigned short* __restrict__ wk2Tb, const unsigned short* __restrict__ wo1b,
    unsigned short* __restrict__ ckb, unsigned short* __restrict__ wv_oTb,
    unsigned short* __restrict__ uwb, float* __restrict__ cb1w)
{
    __shared__ __align__(16) unsigned short cln[2*4224];   // camb | cnb; Phase C: stg overlay (16 KB)
    __shared__ __align__(16) unsigned short kcs [16*264];
    __shared__ __align__(16) unsigned short vcs [16*264];
    __shared__ __align__(16) unsigned short q2s [16*264];
    unsigned short* camb = cln;
    unsigned short* cnb  = cln + 4224;

    int tid = threadIdx.x;
    int wid = tid >> 6, lane = tid & 63;
    int fr = lane & 15, hi4 = lane >> 4, fk = hi4 * 8;
    int bt = blockIdx.x >> 1;
    int hf = blockIdx.x & 1;            // this block handles heads hf*4..hf*4+3
    int r0 = bt * 8;

    // Phase A: 8 cam rows, LN, raw+ln bf16; zero rows 8-15
    {
        float4 g2v = ((const float4*)ln2g)[lane];
        float4 b2v = ((const float4*)ln2b)[lane];
        int row = wid;
        float4 f = ((const float4*)(cam + (size_t)(r0+row)*256))[lane];
        float s  = wredsum(f.x+f.y+f.z+f.w);
        float s2 = wredsum(f.x*f.x+f.y*f.y+f.z*f.z+f.w*f.w);
        float mu = s * (1.f/256.f);
        float rs = rsqrtf(s2*(1.f/256.f) - mu*mu + 1e-5f);
        ushort4 rawv, lnv;
        rawv.x = f2b(f.x); rawv.y = f2b(f.y); rawv.z = f2b(f.z); rawv.w = f2b(f.w);
        lnv.x = f2b((f.x-mu)*rs*g2v.x + b2v.x);
        lnv.y = f2b((f.y-mu)*rs*g2v.y + b2v.y);
        lnv.z = f2b((f.z-mu)*rs*g2v.z + b2v.z);
        lnv.w = f2b((f.w-mu)*rs*g2v.w + b2v.w);
        *(ushort4*)&camb[row*264 + lane*4] = rawv;
        *(ushort4*)&cnb [row*264 + lane*4] = lnv;
        for (int e = tid; e < 2112; e += 512){      // rows 8..15 zeroed
            int off = 8*264 + e;
            camb[off] = 0; cnb[off] = 0; kcs[off] = 0; vcs[off] = 0; q2s[off] = 0;
        }
    }
    __syncthreads();

    // Phase B: 3 GEMMs (kc, vc, q2) restricted to this hf's 128 cols
    for (int u = wid; u < 24; u += 8){
        int gm = u >> 3, nt = u & 7;
        const unsigned short* As = (gm == 2) ? cnb : camb;
        const unsigned short* Bw = (gm == 0) ? wk1b : (gm == 1) ? wv1b : wq2b;
        const float* bias = (gm == 0) ? (bqkv1 + 256) : (gm == 1) ? (bqkv1 + 512) : bqkv2;
        unsigned short* Dst = (gm == 0) ? kcs : (gm == 1) ? vcs : q2s;
        int col = hf*128 + nt*16 + fr;
        float bc = bias[col];
        f32x4 acc = (f32x4){0.f,0.f,0.f,0.f};
        for (int k0 = 0; k0 < 256; k0 += 32){
            bf16x8 a = *(const bf16x8*)&As[fr*264 + k0 + fk];
            bf16x8 b = *(const bf16x8*)&Bw[(size_t)col*256 + k0 + fk];
            acc = __builtin_amdgcn_mfma_f32_16x16x32_bf16(a, b, acc, 0, 0, 0);
        }
        if (hi4 < 2){
            #pragma unroll
            for (int i = 0; i < 4; i++)
                Dst[(hi4*4 + i)*264 + col] = f2b(acc[i] + bc);
        }
    }
    __syncthreads();

    // cb1 for this hf's 4 heads
    if (tid < 32){
        int th = tid >> 3, kk = tid & 7;
        int h = hf*4 + th;
        float a = 0.f;
        for (int j = 0; j < 32; j++)
            a += bqkv1[h*32 + j] * b2f(kcs[kk*264 + h*32 + j]);
        cb1w[(size_t)bt*64 + h*8 + kk] = a;
    }

    // Phase C: 3 rounds (ot); frags -> stg overlay (16 KB), coop 16B stores
    unsigned short* stg = cln;
    for (int ot = 0; ot < 3; ot++){
        const unsigned short* As = (ot == 0) ? kcs : (ot == 1) ? q2s : vcs;
        const unsigned short* Bw = (ot == 0) ? wq1Tb : (ot == 1) ? wk2Tb : wo1b;
        __syncthreads();          // previous round's stg readers (or Phase A/B cln readers) done
        int hp = wid & 3;
        int h  = hf*4 + hp;
        int ntb = (wid >> 2) * 8;
        bf16x8 a = *(const bf16x8*)&As[fr*264 + h*32 + fk];
        for (int nt = ntb; nt < ntb + 8; nt++){
            int col = nt*16 + fr;
            bf16x8 b = *(const bf16x8*)&Bw[(size_t)col*256 + h*32 + fk];
            f32x4 acc = __builtin_amdgcn_mfma_f32_16x16x32_bf16(a, b, (f32x4){0.f,0.f,0.f,0.f}, 0, 0, 0);
            if (hi4 < 2){
                int kk0 = hi4*4;
                if (ot == 0){
                    #pragma unroll
                    for (int i = 0; i < 4; i++) stg[(hp*8 + kk0 + i)*256 + col] = f2b(acc[i]);
                } else if (ot == 1){
                    #pragma unroll
                    for (int i = 0; i < 4; i++) stg[(kk0 + i)*1024 + hp*256 + col] = f2b(acc[i]);
                } else {
                    ushort4 wv;
                    wv.x = f2b(acc[0]); wv.y = f2b(acc[1]); wv.z = f2b(acc[2]); wv.w = f2b(acc[3]);
                    *(ushort4*)&stg[col*32 + hp*8 + kk0] = wv;
                }
            }
        }
        __syncthreads();
        unsigned short* dst = (ot == 0) ? ckb : (ot == 1) ? uwb : wv_oTb;
        for (int cj = tid; cj < 1024; cj += 512){
            bf16x8 v = ((const bf16x8*)stg)[cj];
            size_t go;
            if (ot == 0){
                go = (size_t)bt*16384 + (size_t)hf*8192 + (size_t)cj*8;
            } else if (ot == 1){
                int r = cj >> 7, w = (cj*8) & 1023;
                go = (size_t)bt*16384 + (size_t)r*2048 + (size_t)hf*1024 + w;
            } else {
                int c = cj >> 2, v2 = (cj & 3)*8;
                go = (size_t)bt*16384 + (size_t)c*64 + (size_t)hf*32 + v2;
            }
            *(bf16x8*)(dst + go) = v;
        }
    }
}

// ---------- K2: half-group block (48 rows), stage1 + stage2 partials ----------
// Round-16 config (measured best: 181.9 µs total, k_pose 152.5 µs, VGPR 64,
// occupancy 41%). P4 one column-tile per jt iteration keeps peak VGPR <= 64
// (the 64-reg occupancy step). P2 loads B-fragments direct from ckb (L2-hot).
// P5 re-reads pose (cache-absorbed; xv-in-regs always spills, r8/9/14).
// Occupancy saturates at ~13 waves/CU regardless of residency cap
// (r13: cap 16, r16: cap 20, r17: cap 28 -> all 41%): barrier-chain bound.
__global__ __launch_bounds__(256) void k_pose(
    const float* __restrict__ pose,
    const float* __restrict__ ln1g, const float* __restrict__ ln1b,
    const float* __restrict__ bo1,
    const unsigned short* __restrict__ ckb, const unsigned short* __restrict__ wv_oTb,
    const float* __restrict__ cb1w, const unsigned short* __restrict__ uwb,
    float* __restrict__ out, unsigned short* __restrict__ ypw, float* __restrict__ yms)
{
    __shared__ __align__(16) unsigned short Xs[48*256];   // swizzled: byte^=((row&7)<<4)
    __shared__ __align__(16) unsigned short A1u[48*72];   // A1 | {pb[16][72] @0, sc / ystg @+2560}

    int tid = threadIdx.x;
    int bid = blockIdx.x;
    int g2 = (bid & 7) * 512 + (bid >> 3);     // bijective XCD swizzle (4096 = 8*512)
    int g = g2 >> 1, half = g2 & 1;
    int bt = g >> 3;
    int wid = tid >> 6, lane = tid & 63;
    int fr = lane & 15, hi4 = lane >> 4, fk = hi4 * 8;

    unsigned short (*A1)[72] = (unsigned short(*)[72])A1u;
    float (*sc)[48] = (float(*)[48])((char*)A1u + 2560);

    const float* pbase = pose + (size_t)g*96*256 + (size_t)half*48*256;
    float* obase = out + (size_t)g*96*256 + (size_t)half*48*256;

    int n1 = wid*16 + fr;                       // score col 0..63 (h = n1>>3, kk = n1&7)
    const unsigned short* ckg = ckb + ((size_t)bt*64 + n1) * 256;
    float cb = cb1w[(size_t)bt*64 + n1];

    // P1: LN(pose) -> Xs (pose consumed immediately; NOT kept in regs)
    {
        float4 g1 = ((const float4*)ln1g)[lane];
        float4 b1 = ((const float4*)ln1b)[lane];
        #pragma unroll
        for (int rr = 0; rr < 12; rr++){
            int r = wid + rr*4;
            float4 f = ((const float4*)pbase)[(size_t)r * 64 + lane];
            float s  = wredsum(f.x+f.y+f.z+f.w);
            float s2 = wredsum(f.x*f.x+f.y*f.y+f.z*f.z+f.w*f.w);
            float mu = s * (1.f/256.f);
            float rs = rsqrtf(s2*(1.f/256.f) - mu*mu + 1e-5f);
            ushort4 qv;
            qv.x = f2b((f.x-mu)*rs*g1.x + b1.x);
            qv.y = f2b((f.y-mu)*rs*g1.y + b1.y);
            qv.z = f2b((f.z-mu)*rs*g1.z + b1.z);
            qv.w = f2b((f.w-mu)*rs*g1.w + b1.w);
            *(ushort4*)((char*)Xs + r*512 + ((lane*8) ^ ((r&7)<<4))) = qv;
        }
    }
    __syncthreads();   // b1

    // P2: score GEMM (48x64, K=256) + softmax over kk -> A1
    {
        f32x4 acc[3];
        #pragma unroll
        for (int mt = 0; mt < 3; mt++) acc[mt] = (f32x4){0.f,0.f,0.f,0.f};
        #pragma unroll
        for (int kt = 0; kt < 8; kt++){
            int k0 = kt * 32;
            bf16x8 b = *(const bf16x8*)(ckg + k0 + fk);
            #pragma unroll
            for (int mt = 0; mt < 3; mt++){
                int r = mt*16 + fr;
                bf16x8 a = *(const bf16x8*)((char*)Xs + r*512 + (((k0+fk)*2) ^ ((r&7)<<4)));
                acc[mt] = __builtin_amdgcn_mfma_f32_16x16x32_bf16(a, b, acc[mt], 0, 0, 0);
            }
        }
        #pragma unroll
        for (int mt = 0; mt < 3; mt++){
            #pragma unroll
            for (int i = 0; i < 4; i++){
                float s = (acc[mt][i] + cb) * SCALE1;
                float mx = s;
                mx = fmaxf(mx, __shfl_xor(mx, 1));
                mx = fmaxf(mx, __shfl_xor(mx, 2));
                mx = fmaxf(mx, __shfl_xor(mx, 4));
                float e = __expf(s - mx);
                float sm = e;
                sm += __shfl_xor(sm, 1);
                sm += __shfl_xor(sm, 2);
                sm += __shfl_xor(sm, 4);
                A1[mt*16 + hi4*4 + i][n1] = f2b(e / sm);
            }
        }
    }
    __syncthreads();   // b2

    // P4: PV GEMM (48x256, K=64): one 16-col tile per jt iteration (low reg)
    {
        const unsigned short* wvg = wv_oTb + (size_t)bt * 256 * 64;
        #pragma unroll
        for (int jt = 0; jt < 4; jt++){
            int col = wid*64 + jt*16 + fr;
            f32x4 acc2[3];
            #pragma unroll
            for (int mt = 0; mt < 3; mt++) acc2[mt] = (f32x4){0.f,0.f,0.f,0.f};
            #pragma unroll
            for (int k0 = 0; k0 < 64; k0 += 32){
                bf16x8 b = *(const bf16x8*)(wvg + (size_t)col*64 + k0 + fk);
                #pragma unroll
                for (int mt = 0; mt < 3; mt++){
                    bf16x8 a = *(const bf16x8*)&A1[mt*16 + fr][k0 + fk];
                    acc2[mt] = __builtin_amdgcn_mfma_f32_16x16x32_bf16(a, b, acc2[mt], 0, 0, 0);
                }
            }
            float bias = bo1[col];
            #pragma unroll
            for (int mt = 0; mt < 3; mt++)
                #pragma unroll
                for (int i = 0; i < 4; i++){
                    int row = mt*16 + hi4*4 + i;
                    *(unsigned short*)((char*)Xs + row*512 + ((col*2) ^ ((row&7)<<4))) = f2b(acc2[mt][i] + bias);
                }
        }
    }
    __syncthreads();   // b3

    // P5: residual: re-read pose (cache-absorbed), out = pose + o1(Xs); Xs <- pose_out bf16
    {
        #pragma unroll
        for (int rr = 0; rr < 12; rr++){
            int r = wid + rr*4;
            float4 f = ((const float4*)pbase)[(size_t)r * 64 + lane];
            char* px = (char*)Xs + r*512 + ((lane*8) ^ ((r&7)<<4));
            ushort4 ov = *(ushort4*)px;
            float4 val;
            val.x = f.x + b2f(ov.x);
            val.y = f.y + b2f(ov.y);
            val.z = f.z + b2f(ov.z);
            val.w = f.w + b2f(ov.w);
            *(float4*)(obase + (size_t)r*256 + lane*4) = val;
            ushort4 nv;
            nv.x = f2b(val.x); nv.y = f2b(val.y); nv.z = f2b(val.z); nv.w = f2b(val.w);
            *(ushort4*)px = nv;
        }
    }
    __syncthreads();   // b4

    // P6: stage-2 scores sc[h][n] = SCALE * u_h . x_n  (waves 0-2)
    if (wid < 3){
        const unsigned short* ug = uwb + (size_t)g*2048;
        f32x4 a6 = (f32x4){0.f,0.f,0.f,0.f};
        for (int k0 = 0; k0 < 256; k0 += 32){
            bf16x8 u = *(const bf16x8*)(ug + (size_t)(fr & 7)*256 + k0 + fk); // head fr&7
            int r = wid*16 + fr;
            bf16x8 x = *(const bf16x8*)((char*)Xs + r*512 + (((k0+fk)*2) ^ ((r&7)<<4)));
            a6 = __builtin_amdgcn_mfma_f32_16x16x32_bf16(u, x, a6, 0, 0, 0);
        }
        if (hi4 < 2){
            #pragma unroll
            for (int i = 0; i < 4; i++)
                sc[hi4*4 + i][wid*16 + fr] = a6[i] * SCALE1;
        }
    }
    __syncthreads();   // b5

    // P7: partial softmax (wave 0) -> pb, (m,s) -> yms
    unsigned short (*pb)[72] = (unsigned short(*)[72])A1u;
    if (wid == 0){
        int h = lane >> 3, j = lane & 7;
        float v[6];
        #pragma unroll
        for (int q = 0; q < 6; q++) v[q] = sc[h][j*6 + q];
        float mx = v[0];
        #pragma unroll
        for (int q = 1; q < 6; q++) mx = fmaxf(mx, v[q]);
        mx = fmaxf(mx, __shfl_xor(mx, 1));
        mx = fmaxf(mx, __shfl_xor(mx, 2));
        mx = fmaxf(mx, __shfl_xor(mx, 4));
        float e[6], s = 0.f;
        #pragma unroll
        for (int q = 0; q < 6; q++){ e[q] = __expf(v[q] - mx); s += e[q]; }
        s += __shfl_xor(s, 1);
        s += __shfl_xor(s, 2);
        s += __shfl_xor(s, 4);
        #pragma unroll
        for (int q = 0; q < 6; q++) pb[h][j*6 + q] = f2b(e[q]);
        if (j < 2){
            #pragma unroll
            for (int q = 0; q < 8; q++) pb[h][48 + j*8 + q] = 0;   // zero K-pad 48..63
        }
        if (j == 0){
            yms[(size_t)g2*16 + h*2]     = mx;
            yms[(size_t)g2*16 + h*2 + 1] = s;
        }
    }
    __syncthreads();   // b6

    // P8: partial PV2 -> ystg (dead sc region), coalesced ypw store
    unsigned short* ystg = (unsigned short*)((char*)A1u + 2560);   // [8][256] bf16
    {
        #pragma unroll
        for (int nth = 0; nth < 2; nth++){    // 2 col tiles at a time (reg diet)
            f32x4 ay[2];
            ay[0] = (f32x4){0.f,0.f,0.f,0.f};
            ay[1] = (f32x4){0.f,0.f,0.f,0.f};
            #pragma unroll
            for (int k0 = 0; k0 < 64; k0 += 32){
                bf16x8 a8 = *(const bf16x8*)&pb[fr][k0 + fk];
                #pragma unroll
                for (int nt = 0; nt < 2; nt++){
                    int col = wid*64 + (nth*2+nt)*16 + fr;
                    union { bf16x8 v; unsigned short u[8]; } bx;
                    #pragma unroll
                    for (int jj = 0; jj < 8; jj++){
                        int rr = k0 + fk + jj;
                        rr = (rr < 48) ? rr : 47;  // clamp: rows 48-63 zero in A; B must stay finite
                        bx.u[jj] = *(const unsigned short*)((char*)Xs + rr*512 + ((col*2) ^ ((rr&7)<<4)));
                    }
                    ay[nt] = __builtin_amdgcn_mfma_f32_16x16x32_bf16(a8, bx.v, ay[nt], 0, 0, 0);
                }
            }
            if (hi4 < 2){
                #pragma unroll
                for (int nt = 0; nt < 2; nt++)
                    #pragma unroll
                    for (int i = 0; i < 4; i++)
                        ystg[(hi4*4 + i)*256 + wid*64 + (nth*2+nt)*16 + fr] = f2b(ay[nt][i]);
            }
        }
    }
    __syncthreads();   // b7
    ((bf16x8*)(ypw + (size_t)g2*2048))[tid] = ((const bf16x8*)ystg)[tid];
}

// ---------- K3: per-bt combine + camera matvecs via MFMA (256 blocks) ----------
__global__ __launch_bounds__(512) void k_cam2(
    const float* __restrict__ cam,
    const float* __restrict__ bqkv2, const float* __restrict__ bo2,
    const unsigned short* __restrict__ wv2b, const unsigned short* __restrict__ wo2b,
    const unsigned short* __restrict__ ypw, const float* __restrict__ yms,
    float* __restrict__ out)
{
    __shared__ __align__(16) unsigned short ycb[8][16][264];  // [h][g pad16][256 pad]
    __shared__ __align__(16) unsigned short o2s[16][264];     // o2 bf16, rows g pad16
    __shared__ __align__(16) float wf[8][8][2];               // [gl][h]{f0,f1}

    int tid = threadIdx.x;
    int bt = blockIdx.x;
    int wid = tid >> 6, lane = tid & 63;
    int fr = lane & 15, hi4 = lane >> 4, fk = hi4 * 8;

    // zero pad rows (g=8..15): finite A-rows for MFMA
    for (int e = tid; e < 16896; e += 512)
        ((unsigned short*)ycb)[(e/2112)*16*264 + (8 + (e%2112)/264)*264 + (e%264)] = 0;
    for (int e = tid; e < 2112; e += 512) o2s[8 + e/264][e%264] = 0;

    // combine factors
    if (tid < 64){
        int gl = tid >> 3, h = tid & 7;
        const float* ms0 = yms + (size_t)(bt*16 + gl*2)*16 + h*2;
        float m0 = ms0[0], s0 = ms0[1];
        float m1 = ms0[16], s1 = ms0[17];
        float m = fmaxf(m0, m1);
        float w0 = __expf(m0 - m), w1 = __expf(m1 - m);
        float inv = 1.f / (s0*w0 + s1*w1);
        wf[gl][h][0] = w0*inv; wf[gl][h][1] = w1*inv;
    }
    __syncthreads();

    // combine partials -> ycb bf16
    for (int e = tid; e < 2048; e += 512){
        int gl = e >> 8, rest = e & 255, h = rest >> 5, i8 = rest & 31;
        const unsigned short* y0 = ypw + (size_t)(bt*16 + gl*2)*2048 + h*256 + i8*8;
        bf16x8 v0 = *(const bf16x8*)y0;
        bf16x8 v1 = *(const bf16x8*)(y0 + 2048);
        float f0 = wf[gl][h][0], f1 = wf[gl][h][1];
        union { bf16x8 v; unsigned short u[8]; } rr;
        #pragma unroll
        for (int q = 0; q < 8; q++)
            rr.u[q] = f2b(b2f((unsigned short)v0[q])*f0 + b2f((unsigned short)v1[q])*f1);
        *(bf16x8*)&ycb[h][gl][i8*8] = rr.v;
    }
    __syncthreads();

    // GEMM o2: per head h, D[g][j] = ycb_h @ wv2_h^T + bv2 (M=16pad, N=32, K=256)
    for (int u = wid; u < 16; u += 8){
        int h = u >> 1, nt = u & 1;
        int m = h*32 + nt*16 + fr;
        f32x4 acc = (f32x4){0.f,0.f,0.f,0.f};
        for (int k0 = 0; k0 < 256; k0 += 32){
            bf16x8 a = *(const bf16x8*)&ycb[h][fr][k0 + fk];
            bf16x8 b = *(const bf16x8*)(wv2b + (size_t)m*256 + k0 + fk);
            acc = __builtin_amdgcn_mfma_f32_16x16x32_bf16(a, b, acc, 0, 0, 0);
        }
        if (hi4 < 2){
            float bv = bqkv2[512 + m];
            #pragma unroll
            for (int i = 0; i < 4; i++)
                o2s[hi4*4 + i][m] = f2b(acc[i] + bv);
        }
    }
    __syncthreads();

    // GEMM cam_out: D[g][c] = o2s @ wo2^T + bo2 + cam (M=16pad, N=256, K=256)
    const float* camg = cam + (size_t)bt*8*256;
    float* og = out + POSE_ELEMS + (size_t)bt*8*256;
    for (int u = wid; u < 16; u += 8){
        int col = u*16 + fr;
        f32x4 acc = (f32x4){0.f,0.f,0.f,0.f};
        for (int k0 = 0; k0 < 256; k0 += 32){
            bf16x8 a = *(const bf16x8*)&o2s[fr][k0 + fk];
            bf16x8 b = *(const bf16x8*)(wo2b + (size_t)col*256 + k0 + fk);
            acc = __builtin_amdgcn_mfma_f32_16x16x32_bf16(a, b, acc, 0, 0, 0);
        }
        if (hi4 < 2){
            float bc = bo2[col];
            #pragma unroll
            for (int i = 0; i < 4; i++){
                int gg = hi4*4 + i;
                og[(size_t)gg*256 + col] = acc[i] + bc + camg[(size_t)gg*256 + col];
            }
        }
    }
}

extern "C" void kernel_launch(void* const* d_in, const int* in_sizes, int n_in,
                              void* d_out, int out_size, void* d_ws, size_t ws_size,
                              hipStream_t stream)
{
    const float* pose  = (const float*)d_in[0];
    const float* camr  = (const float*)d_in[1];
    const float* ln1g  = (const float*)d_in[2];
    const float* ln1b  = (const float*)d_in[3];
    const float* wqkv1 = (const float*)d_in[4];
    const float* bqkv1 = (const float*)d_in[5];
    const float* wo1   = (const float*)d_in[6];
    const float* bo1   = (const float*)d_in[7];
    const float* ln2g  = (const float*)d_in[8];
    const float* ln2b  = (const float*)d_in[9];
    const float* wqkv2 = (const float*)d_in[10];
    const float* bqkv2 = (const float*)d_in[11];
    const float* wo2   = (const float*)d_in[12];
    const float* bo2   = (const float*)d_in[13];
    float* out = (float*)d_out;
    char* ws = (char*)d_ws;

    // ws layout (~41.5 MB)
    size_t off = 0;
    unsigned short* ckb    = (unsigned short*)(ws + off); off += 8388608;          // [256][64][256] bf16
    unsigned short* wv_oTb = (unsigned short*)(ws + off); off += 8388608;          // [256][256][64] bf16
    unsigned short* uwb    = (unsigned short*)(ws + off); off += 8388608 + 8192;   // [2048][2048] bf16 + pad
    unsigned short* ypw    = (unsigned short*)(ws + off); off += 16777216;         // [4096][8][256] bf16
    float*          yms    = (float*)(ws + off);          off += 262144;           // [4096][8][2] f32
    unsigned short* wts    = (unsigned short*)(ws + off); off += 8*131072;
    unsigned short* wk1b  = wts;
    unsigned short* wv1b  = wts + 1*65536;
    unsigned short* wq2b  = wts + 2*65536;
    unsigned short* wq1Tb = wts + 3*65536;
    unsigned short* wk2Tb = wts + 4*65536;
    unsigned short* wo1b  = wts + 5*65536;
    unsigned short* wv2b  = wts + 6*65536;
    unsigned short* wo2b  = wts + 7*65536;
    float* cb1w = (float*)(ws + off);                      off += 65536;

    k_conv2<<<dim3(256), dim3(256), 0, stream>>>(wqkv1, wo1, wqkv2, wo2,
                                                 wk1b, wv1b, wq2b, wq1Tb, wk2Tb, wo1b, wv2b, wo2b);
    k_prep2<<<dim3(512), dim3(512), 0, stream>>>(camr, ln2g, ln2b, bqkv1, bqkv2,
                                                 wk1b, wv1b, wq2b, wq1Tb, wk2Tb, wo1b,
                                                 ckb, wv_oTb, uwb, cb1w);
    k_pose<<<dim3(4096), dim3(256), 0, stream>>>(pose, ln1g, ln1b, bo1,
                                                 ckb, wv_oTb, cb1w, uwb, out, ypw, yms);
    k_cam2<<<dim3(256), dim3(512), 0, stream>>>(camr, bqkv2, bo2, wv2b, wo2b, ypw, yms, out);
}